// Round 1
// baseline (299.787 us; speedup 1.0000x reference)
//
#include <hip/hip_runtime.h>
#include <cstddef>

// Problem constants
// z: (8, 256, 16,16,16) fp32; embedding: (1024, 256) fp32
// N = 8*4096 = 32768 latent vectors, C=256, K=1024
#define BATCH 8
#define CDIM 256
#define SPAT 4096            // 16*16*16
#define NVEC 32768           // BATCH*SPAT
#define KCODE 1024

#define ZQ_SIZE 8388608      // 8*256*4096
#define LOSS_OFF 8388608
#define PERP_OFF 8388609
#define IDX_OFF  8388610

// ---------------------------------------------------------------------------
// Kernel 1: enorm[k] = sum_c e[k][c]^2 ; zero counts + loss accumulator
// grid 256 blocks x 256 threads, one wave per code
// ---------------------------------------------------------------------------
__global__ __launch_bounds__(256) void vq_prep(const float* __restrict__ emb,
                                               float* __restrict__ enorm,
                                               float* __restrict__ counts,
                                               float* __restrict__ losssum) {
    int tid = threadIdx.x;
    if (blockIdx.x == 0) {
        for (int i = tid; i < KCODE; i += 256) counts[i] = 0.0f;
        if (tid == 0) losssum[0] = 0.0f;
    }
    int w = tid >> 6, lane = tid & 63;
    int k = blockIdx.x * 4 + w;
    const float* row = emb + (size_t)k * CDIM;
    float s = 0.0f;
#pragma unroll
    for (int i = 0; i < 4; ++i) {
        float v = row[lane + 64 * i];
        s = fmaf(v, v, s);
    }
#pragma unroll
    for (int m = 32; m > 0; m >>= 1) s += __shfl_xor(s, m, 64);
    if (lane == 0) enorm[k] = s;
}

// ---------------------------------------------------------------------------
// Kernel 2: fused distance-GEMM + argmin + gather + loss partials + counts
// grid 512 blocks (64 columns each) x 256 threads
// thread mapping: cx = tid&7 (8 col-groups of 8 cols), ky = tid>>3 (32 code-
// groups of 8 codes) -> 256-code tile; 4 tiles cover K=1024.
// LDS: zt[256][64] persists the z-tile; et[8][256] stages e-chunks.
// ---------------------------------------------------------------------------
__global__ __launch_bounds__(256, 2) void vq_main(const float* __restrict__ z,
                                                  const float* __restrict__ emb,
                                                  const float* __restrict__ enorm,
                                                  float* __restrict__ counts,
                                                  float* __restrict__ losssum,
                                                  float* __restrict__ out) {
    __shared__ float zt[CDIM * 64];   // 64 KB, [c][col]
    __shared__ float et[8 * 256];     // 8 KB,  [cc][kk]
    __shared__ float zzs[64];
    __shared__ float red_s[4 * 64];
    __shared__ int   red_i[4 * 64];
    __shared__ int   bidx[64];

    const int tid = threadIdx.x;
    const int n0 = blockIdx.x * 64;        // first global column
    const int b = n0 >> 12;                // batch (4096 cols per batch, 64 | 4096)
    const int sp0 = n0 & 4095;
    const float* zb = z + (size_t)b * CDIM * SPAT + sp0;

    // ---- stage z-tile (coalesced: 16 lanes x float4 = 256B per c-row) ----
    for (int i = tid; i < CDIM * 16; i += 256) {
        int c = i >> 4, seg = i & 15;
        float4 v = *(const float4*)(zb + (size_t)c * SPAT + seg * 4);
        *(float4*)&zt[c * 64 + seg * 4] = v;
    }
    __syncthreads();

    // ---- zz per column (np: sum(zf*zf, axis=1)) ----
    if (tid < 64) {
        float s = 0.0f;
        for (int c = 0; c < CDIM; ++c) {
            float v = zt[c * 64 + tid];
            s = fmaf(v, v, s);
        }
        zzs[tid] = s;
    }
    __syncthreads();

    const int cx = tid & 7;   // column group: cols 8*cx .. 8*cx+7
    const int ky = tid >> 3;  // code group within tile: codes 8*ky .. 8*ky+7

    float zzv[8];
    {
        float4 za = *(const float4*)&zzs[cx * 8];
        float4 zc = *(const float4*)&zzs[cx * 8 + 4];
        zzv[0] = za.x; zzv[1] = za.y; zzv[2] = za.z; zzv[3] = za.w;
        zzv[4] = zc.x; zzv[5] = zc.y; zzv[6] = zc.z; zzv[7] = zc.w;
    }

    float bs[8];
    int   bi[8];
#pragma unroll
    for (int j = 0; j < 8; ++j) { bs[j] = 3.4e38f; bi[j] = 0; }

    for (int t = 0; t < 4; ++t) {
        const int k0 = t * 256;
        float acc[8][8];
#pragma unroll
        for (int i = 0; i < 8; ++i)
#pragma unroll
            for (int j = 0; j < 8; ++j) acc[i][j] = 0.0f;

        const float* ebase = emb + (size_t)(k0 + tid) * CDIM;
        float4 ea = *(const float4*)(ebase);
        float4 eb = *(const float4*)(ebase + 4);

        for (int c0 = 0; c0 < CDIM; c0 += 8) {
            __syncthreads();   // previous chunk's compute done
            // store staged chunk: et[cc][kk], kk = tid (conflict-free writes)
            et[0 * 256 + tid] = ea.x; et[1 * 256 + tid] = ea.y;
            et[2 * 256 + tid] = ea.z; et[3 * 256 + tid] = ea.w;
            et[4 * 256 + tid] = eb.x; et[5 * 256 + tid] = eb.y;
            et[6 * 256 + tid] = eb.z; et[7 * 256 + tid] = eb.w;
            __syncthreads();
            // prefetch next chunk while computing this one
            if (c0 < CDIM - 8) {
                ea = *(const float4*)(ebase + c0 + 8);
                eb = *(const float4*)(ebase + c0 + 12);
            }
#pragma unroll
            for (int cc = 0; cc < 8; ++cc) {
                const int c = c0 + cc;
                float4 a0 = *(const float4*)&zt[c * 64 + cx * 8];
                float4 a1 = *(const float4*)&zt[c * 64 + cx * 8 + 4];
                float4 b0 = *(const float4*)&et[cc * 256 + ky * 8];
                float4 b1 = *(const float4*)&et[cc * 256 + ky * 8 + 4];
                float zv[8] = {a0.x, a0.y, a0.z, a0.w, a1.x, a1.y, a1.z, a1.w};
                float ev[8] = {b0.x, b0.y, b0.z, b0.w, b1.x, b1.y, b1.z, b1.w};
#pragma unroll
                for (int i = 0; i < 8; ++i)
#pragma unroll
                    for (int j = 0; j < 8; ++j)
                        acc[i][j] = fmaf(ev[i], zv[j], acc[i][j]);
            }
        }

        // tile epilogue: replicate np's d = fp32(zz + ee) - 2*M quantization
        float en[8];
        {
            const float* ep = enorm + k0 + ky * 8;
            float4 e0 = *(const float4*)(ep);
            float4 e1 = *(const float4*)(ep + 4);
            en[0] = e0.x; en[1] = e0.y; en[2] = e0.z; en[3] = e0.w;
            en[4] = e1.x; en[5] = e1.y; en[6] = e1.z; en[7] = e1.w;
        }
#pragma unroll
        for (int i = 0; i < 8; ++i) {
            const int k = k0 + ky * 8 + i;
#pragma unroll
            for (int j = 0; j < 8; ++j) {
                float tt = zzv[j] + en[i];       // rounded like np (zz+ee)
                float d = tt - 2.0f * acc[i][j]; // 2*M exact, one rounding
                if (d < bs[j]) { bs[j] = d; bi[j] = k; }  // ascending k: ties keep lowest
            }
        }
    }

    // ---- merge across ky within wave (lane bits 3..5), tie-break low index ----
#pragma unroll
    for (int m = 8; m <= 32; m <<= 1) {
#pragma unroll
        for (int j = 0; j < 8; ++j) {
            float s2 = __shfl_xor(bs[j], m, 64);
            int   i2 = __shfl_xor(bi[j], m, 64);
            if (s2 < bs[j] || (s2 == bs[j] && i2 < bi[j])) { bs[j] = s2; bi[j] = i2; }
        }
    }
    {
        int w = tid >> 6, lane = tid & 63;
        if (lane < 8) {
#pragma unroll
            for (int j = 0; j < 8; ++j) {
                red_s[w * 64 + lane * 8 + j] = bs[j];
                red_i[w * 64 + lane * 8 + j] = bi[j];
            }
        }
    }
    __syncthreads();
    if (tid < 64) {
        float s = red_s[tid];
        int ki = red_i[tid];
#pragma unroll
        for (int w2 = 1; w2 < 4; ++w2) {
            float s2 = red_s[w2 * 64 + tid];
            int k2 = red_i[w2 * 64 + tid];
            if (s2 < s || (s2 == s && k2 < ki)) { s = s2; ki = k2; }
        }
        out[IDX_OFF + n0 + tid] = (float)ki;
        atomicAdd(&counts[ki], 1.0f);
        bidx[tid] = ki;
    }
    __syncthreads();

    // ---- gather z_q, STE output zp + (q - zp), loss partial ----
    float ls = 0.0f;
    float* outz = out + (size_t)b * CDIM * SPAT + sp0;
    for (int i = tid; i < CDIM * 16; i += 256) {
        int c = i >> 4, seg = i & 15;
        float4 zp = *(const float4*)&zt[c * 64 + seg * 4];
        int kk0 = bidx[seg * 4 + 0];
        int kk1 = bidx[seg * 4 + 1];
        int kk2 = bidx[seg * 4 + 2];
        int kk3 = bidx[seg * 4 + 3];
        float q0 = emb[(size_t)kk0 * CDIM + c];
        float q1 = emb[(size_t)kk1 * CDIM + c];
        float q2 = emb[(size_t)kk2 * CDIM + c];
        float q3 = emb[(size_t)kk3 * CDIM + c];
        float d0 = q0 - zp.x, d1 = q1 - zp.y, d2 = q2 - zp.z, d3 = q3 - zp.w;
        float4 o;
        o.x = zp.x + d0; o.y = zp.y + d1; o.z = zp.z + d2; o.w = zp.w + d3;
        ls = fmaf(d0, d0, ls); ls = fmaf(d1, d1, ls);
        ls = fmaf(d2, d2, ls); ls = fmaf(d3, d3, ls);
        *(float4*)(outz + (size_t)c * SPAT + seg * 4) = o;
    }
#pragma unroll
    for (int m = 32; m > 0; m >>= 1) ls += __shfl_xor(ls, m, 64);
    if ((tid & 63) == 0) atomicAdd(losssum, ls);
}

// ---------------------------------------------------------------------------
// Kernel 3: loss + perplexity
// ---------------------------------------------------------------------------
__global__ __launch_bounds__(256) void vq_finalize(const float* __restrict__ counts,
                                                   const float* __restrict__ losssum,
                                                   float* __restrict__ out) {
    __shared__ float red[256];
    int tid = threadIdx.x;
    float s = 0.0f;
    for (int k = tid; k < KCODE; k += 256) {
        float em = counts[k] * (1.0f / 32768.0f);
        s += em * logf(em + 1e-10f);
    }
    red[tid] = s;
    __syncthreads();
    for (int off = 128; off > 0; off >>= 1) {
        if (tid < off) red[tid] += red[tid + off];
        __syncthreads();
    }
    if (tid == 0) {
        float m = losssum[0] * (1.0f / 8388608.0f);
        out[LOSS_OFF] = m + 0.25f * m;   // legacy: mean1 + beta*mean2, equal values
        out[PERP_OFF] = expf(-red[0]);
    }
}

extern "C" void kernel_launch(void* const* d_in, const int* in_sizes, int n_in,
                              void* d_out, int out_size, void* d_ws, size_t ws_size,
                              hipStream_t stream) {
    const float* z = (const float*)d_in[0];
    const float* emb = (const float*)d_in[1];
    float* out = (float*)d_out;
    float* enorm = (float*)d_ws;        // 1024 floats
    float* counts = enorm + KCODE;      // 1024 floats
    float* losssum = counts + KCODE;    // 1 float

    vq_prep<<<256, 256, 0, stream>>>(emb, enorm, counts, losssum);
    vq_main<<<512, 256, 0, stream>>>(z, emb, enorm, counts, losssum, out);
    vq_finalize<<<1, 256, 0, stream>>>(counts, losssum, out);
}